// Round 4
// baseline (686.376 us; speedup 1.0000x reference)
//
#include <hip/hip_runtime.h>

typedef __bf16 bf16_t;
typedef __attribute__((ext_vector_type(8))) __bf16 bf16x8;
typedef __attribute__((ext_vector_type(4))) float f32x4;

#define NB 16
#define NC 768
#define NT 1025
#define TP 1088            /* 17 * 64 */
#define NH 12
#define DH 64
#define QK_SCALE 0.03608439182435161f  /* 1/sqrt(768) */

// ---------------- QKV depthwise conv + BN (register-blocked) ----------------
__global__ __launch_bounds__(256) void qkv_conv(
    const float* __restrict__ x,
    const float* __restrict__ wq, const float* __restrict__ gq, const float* __restrict__ bq,
    const float* __restrict__ mq, const float* __restrict__ vq,
    const float* __restrict__ wk, const float* __restrict__ gk, const float* __restrict__ bk,
    const float* __restrict__ mk, const float* __restrict__ vk,
    const float* __restrict__ wv, const float* __restrict__ gv, const float* __restrict__ bv,
    const float* __restrict__ mv, const float* __restrict__ vv,
    bf16_t* __restrict__ Q, bf16_t* __restrict__ K, bf16_t* __restrict__ V)
{
    const int tid = threadIdx.x;
    const int c  = blockIdx.y * 256 + tid;
    const int y0 = blockIdx.x * 4;
    const int b  = blockIdx.z;

    const float* xb = x + ((size_t)b * NT + 1) * NC + c;

    float WQ[9], WK[9], WV[9];
#pragma unroll
    for (int k = 0; k < 9; ++k) {
        WQ[k] = wq[c * 9 + k];
        WK[k] = wk[c * 9 + k];
        WV[k] = wv[c * 9 + k];
    }
    float sq = gq[c] * rsqrtf(vq[c] + 1e-5f);
    float tq = (bq[c] - mq[c] * sq) * QK_SCALE; sq *= QK_SCALE;
    float sk = gk[c] * rsqrtf(vk[c] + 1e-5f);
    float tk = bk[c] - mk[c] * sk;
    float sv = gv[c] * rsqrtf(vv[c] + 1e-5f);
    float tv = bv[c] - mv[c] * sv;

    const int h = c >> 6, dk = c & 63;
    bf16_t* Qo = Q + ((size_t)(b * NH + h) * TP + 1 + y0 * 32) * DH + dk;
    bf16_t* Ko = K + ((size_t)(b * NH + h) * TP + 1 + y0 * 32) * DH + dk;
    bf16_t* Vo = V + ((size_t)(b * NH + h) * TP + 1 + y0 * 32) * DH + dk;

    float win[6][3];
#pragma unroll
    for (int r = 0; r < 6; ++r) {
        int yy = y0 - 1 + r;
        win[r][0] = 0.f;
        win[r][1] = (yy >= 0 && yy < 32) ? xb[(size_t)(yy * 32) * NC] : 0.f;
    }

#pragma unroll 4
    for (int xo = 0; xo < 32; ++xo) {
#pragma unroll
        for (int r = 0; r < 6; ++r) {
            int yy = y0 - 1 + r;
            win[r][2] = (xo < 31 && yy >= 0 && yy < 32)
                        ? xb[(size_t)(yy * 32 + xo + 1) * NC] : 0.f;
        }
#pragma unroll
        for (int r = 0; r < 4; ++r) {
            float aq = 0.f, ak = 0.f, av = 0.f;
#pragma unroll
            for (int dy = 0; dy < 3; ++dy) {
#pragma unroll
                for (int dx = 0; dx < 3; ++dx) {
                    float xv = win[r + dy][dx];
                    aq += xv * WQ[dy * 3 + dx];
                    ak += xv * WK[dy * 3 + dx];
                    av += xv * WV[dy * 3 + dx];
                }
            }
            size_t o = ((size_t)(r * 32 + xo)) * DH;
            Qo[o] = (bf16_t)(aq * sq + tq);
            Ko[o] = (bf16_t)(ak * sk + tk);
            Vo[o] = (bf16_t)(av * sv + tv);
        }
#pragma unroll
        for (int r = 0; r < 6; ++r) {
            win[r][0] = win[r][1];
            win[r][1] = win[r][2];
        }
    }
}

__global__ __launch_bounds__(256) void cls_fill(
    const float* __restrict__ x, bf16_t* __restrict__ Q, bf16_t* __restrict__ K, bf16_t* __restrict__ V)
{
    int idx = blockIdx.x * 256 + threadIdx.x;
    int c = idx % NC;
    int b = idx / NC;
    float xv = x[(size_t)b * NT * NC + c];
    int h = c >> 6, dk = c & 63;
    size_t base = ((size_t)(b * NH + h) * TP + 0) * DH + dk;
    Q[base] = (bf16_t)(xv * QK_SCALE);
    K[base] = (bf16_t)xv;
    V[base] = (bf16_t)xv;
}

// ---------------- V transpose: [bh][t][64] -> [bh][64][t] ----------------
__global__ __launch_bounds__(256) void transpose_v(
    const bf16_t* __restrict__ V, bf16_t* __restrict__ Vt)
{
    __shared__ bf16_t tile[64][65];
    int bh = blockIdx.y;
    int t0 = blockIdx.x * 64;
    for (int i = threadIdx.x; i < 64 * 64; i += 256) {
        int tt = i >> 6, dk = i & 63;
        tile[tt][dk] = V[((size_t)bh * TP + t0 + tt) * DH + dk];
    }
    __syncthreads();
    for (int i = threadIdx.x; i < 64 * 64; i += 256) {
        int dk = i >> 6, tt = i & 63;
        Vt[((size_t)bh * DH + dk) * TP + t0 + tt] = tile[tt][dk];
    }
}

// ---------------- flash attention ----------------
// 2 waves/block, each wave owns 16 Q rows; KVBLK=64; defer-max; no barriers
// (pl is wave-private); XCD-swizzled block ids for K/V L2 locality.
__global__ __launch_bounds__(128) void attn_kernel(
    const bf16_t* __restrict__ Q, const bf16_t* __restrict__ K,
    const bf16_t* __restrict__ Vt, bf16_t* __restrict__ Oa)
{
    int bid = blockIdx.x;                       // 192*33 = 6336
    int swz = (bid & 7) * 792 + (bid >> 3);     // 8 XCDs, 792 blocks each
    int bh = swz / 33;
    int qp = swz % 33;
    int wid = threadIdx.x >> 6;
    int lane = threadIdx.x & 63;
    int qt = qp * 2 + wid;                      // 0..65
    int b = bh / NH, h = bh % NH;
    int cl = lane & 15, gr = lane >> 4;

    const bf16_t* Qb = Q + ((size_t)bh * TP + qt * 16) * DH;
    const bf16_t* Kb = K + (size_t)bh * TP * DH;
    const bf16_t* Vb = Vt + (size_t)bh * DH * TP;

    bf16x8 qf0 = *(const bf16x8*)(Qb + cl * DH + gr * 8);
    bf16x8 qf1 = *(const bf16x8*)(Qb + cl * DH + 32 + gr * 8);

    f32x4 o0 = {0.f, 0.f, 0.f, 0.f}, o1 = o0, o2 = o0, o3 = o0;
    float mrow[4] = {-1e30f, -1e30f, -1e30f, -1e30f};
    float lrow[4] = {0.f, 0.f, 0.f, 0.f};

    __shared__ alignas(16) bf16_t pl[2][16][72];   // stride 72: aligned b128 reads
    bf16_t (*pw)[72] = pl[wid];

    for (int kt = 0; kt < 17; ++kt) {
        int t0 = kt * 64;
        f32x4 s[4];
#pragma unroll
        for (int st = 0; st < 4; ++st) { s[st][0]=0.f; s[st][1]=0.f; s[st][2]=0.f; s[st][3]=0.f; }
#pragma unroll
        for (int st = 0; st < 4; ++st) {
            const bf16_t* K0 = Kb + (size_t)(t0 + st * 16 + cl) * DH;
            s[st] = __builtin_amdgcn_mfma_f32_16x16x32_bf16(qf0, *(const bf16x8*)(K0 + gr * 8), s[st], 0, 0, 0);
            s[st] = __builtin_amdgcn_mfma_f32_16x16x32_bf16(qf1, *(const bf16x8*)(K0 + 32 + gr * 8), s[st], 0, 0, 0);
        }
        // mask padded key columns
#pragma unroll
        for (int st = 0; st < 4; ++st) {
            if (t0 + st * 16 + cl >= NT) {
                s[st][0] = -1e30f; s[st][1] = -1e30f; s[st][2] = -1e30f; s[st][3] = -1e30f;
            }
        }
        // per-row tile max (row = gr*4+j, reduce over st + 16 cl lanes)
        float mx[4];
#pragma unroll
        for (int j = 0; j < 4; ++j) {
            float m_ = fmaxf(fmaxf(s[0][j], s[1][j]), fmaxf(s[2][j], s[3][j]));
            m_ = fmaxf(m_, __shfl_xor(m_, 1));
            m_ = fmaxf(m_, __shfl_xor(m_, 2));
            m_ = fmaxf(m_, __shfl_xor(m_, 4));
            m_ = fmaxf(m_, __shfl_xor(m_, 8));
            mx[j] = m_;
        }
        // defer-max: only rescale when some row's max grew by > 8
        bool need = (mx[0] > mrow[0] + 8.f) || (mx[1] > mrow[1] + 8.f) ||
                    (mx[2] > mrow[2] + 8.f) || (mx[3] > mrow[3] + 8.f);
        if (__ballot(need)) {
#pragma unroll
            for (int j = 0; j < 4; ++j) {
                float mn = fmaxf(mrow[j], mx[j]);
                float al = __expf(mrow[j] - mn);
                mrow[j] = mn;
                lrow[j] *= al;
                o0[j] *= al; o1[j] *= al; o2[j] *= al; o3[j] *= al;
            }
        }
#pragma unroll
        for (int j = 0; j < 4; ++j) {
            float p0 = __expf(s[0][j] - mrow[j]);
            float p1 = __expf(s[1][j] - mrow[j]);
            float p2 = __expf(s[2][j] - mrow[j]);
            float p3 = __expf(s[3][j] - mrow[j]);
            s[0][j] = p0; s[1][j] = p1; s[2][j] = p2; s[3][j] = p3;
            float r = (p0 + p1) + (p2 + p3);
            r += __shfl_xor(r, 1);
            r += __shfl_xor(r, 2);
            r += __shfl_xor(r, 4);
            r += __shfl_xor(r, 8);
            lrow[j] += r;
        }
        // P tile (16 x 64) through wave-private LDS to A-fragment layout
#pragma unroll
        for (int j = 0; j < 4; ++j)
#pragma unroll
            for (int st = 0; st < 4; ++st)
                pw[gr * 4 + j][st * 16 + cl] = (bf16_t)s[st][j];
        asm volatile("s_waitcnt lgkmcnt(0)" ::: "memory");
#pragma unroll
        for (int tb = 0; tb < 2; ++tb) {
            bf16x8 pa = *(const bf16x8*)(&pw[cl][tb * 32 + gr * 8]);
            const bf16_t* V0 = Vb + t0 + tb * 32 + gr * 8;
            o0 = __builtin_amdgcn_mfma_f32_16x16x32_bf16(pa, *(const bf16x8*)(V0 + (size_t)(0 * 16 + cl) * TP), o0, 0, 0, 0);
            o1 = __builtin_amdgcn_mfma_f32_16x16x32_bf16(pa, *(const bf16x8*)(V0 + (size_t)(1 * 16 + cl) * TP), o1, 0, 0, 0);
            o2 = __builtin_amdgcn_mfma_f32_16x16x32_bf16(pa, *(const bf16x8*)(V0 + (size_t)(2 * 16 + cl) * TP), o2, 0, 0, 0);
            o3 = __builtin_amdgcn_mfma_f32_16x16x32_bf16(pa, *(const bf16x8*)(V0 + (size_t)(3 * 16 + cl) * TP), o3, 0, 0, 0);
        }
    }

    int tr0 = qt * 16;
#pragma unroll
    for (int j = 0; j < 4; ++j) {
        int t = tr0 + gr * 4 + j;
        if (t < NT) {
            float inv = 1.0f / lrow[j];
            size_t row = ((size_t)b * NT + t) * NC + h * DH;
            Oa[row + 0 * 16 + cl] = (bf16_t)(o0[j] * inv);
            Oa[row + 1 * 16 + cl] = (bf16_t)(o1[j] * inv);
            Oa[row + 2 * 16 + cl] = (bf16_t)(o2[j] * inv);
            Oa[row + 3 * 16 + cl] = (bf16_t)(o3[j] * inv);
        }
    }
}

__global__ __launch_bounds__(256) void conv_w(const float* __restrict__ W, bf16_t* __restrict__ Wb)
{
    int i = blockIdx.x * 256 + threadIdx.x;
    if (i < NC * NC) Wb[i] = (bf16_t)W[i];
}

// ---------------- projection GEMM: 32-row waves, B-frags shared ----------------
__global__ __launch_bounds__(64) void proj_gemm(
    const bf16_t* __restrict__ Oa, const bf16_t* __restrict__ Wb,
    const float* __restrict__ bias, float* __restrict__ out)
{
    int wid = blockIdx.x;          // 513 * 12
    int nt = wid % 12;             // 64-col tile
    int mt = wid / 12;             // 32-row tile (last one half-masked)
    int lane = threadIdx.x;
    int cl = lane & 15, gr = lane >> 4;

    const bf16_t* A0 = Oa + ((size_t)mt * 32 + cl) * NC + gr * 8;
    const bf16_t* A1 = A0 + (size_t)16 * NC;
    const bf16_t* Bp = Wb + ((size_t)(nt * 64 + cl)) * NC + gr * 8;
    f32x4 acc[2][4];
#pragma unroll
    for (int a = 0; a < 2; ++a)
#pragma unroll
        for (int j = 0; j < 4; ++j) { acc[a][j][0]=0.f; acc[a][j][1]=0.f; acc[a][j][2]=0.f; acc[a][j][3]=0.f; }
#pragma unroll 2
    for (int ks = 0; ks < 24; ++ks) {
        bf16x8 af0 = *(const bf16x8*)(A0 + ks * 32);
        bf16x8 af1 = *(const bf16x8*)(A1 + ks * 32);
#pragma unroll
        for (int j = 0; j < 4; ++j) {
            bf16x8 bf = *(const bf16x8*)(Bp + (size_t)j * 16 * NC + ks * 32);
            acc[0][j] = __builtin_amdgcn_mfma_f32_16x16x32_bf16(af0, bf, acc[0][j], 0, 0, 0);
            acc[1][j] = __builtin_amdgcn_mfma_f32_16x16x32_bf16(af1, bf, acc[1][j], 0, 0, 0);
        }
    }
#pragma unroll
    for (int a = 0; a < 2; ++a)
#pragma unroll
    for (int j = 0; j < 4; ++j) {
        int col = nt * 64 + j * 16 + cl;
        float bv = bias[col];
#pragma unroll
        for (int jj = 0; jj < 4; ++jj) {
            int r = mt * 32 + a * 16 + gr * 4 + jj;
            if (r < NB * NT)
                out[(size_t)r * NC + col] = acc[a][j][jj] + bv;
        }
    }
}

extern "C" void kernel_launch(void* const* d_in, const int* in_sizes, int n_in,
                              void* d_out, int out_size, void* d_ws, size_t ws_size,
                              hipStream_t stream)
{
    const float* x = (const float*)d_in[0];
    const float* wq = (const float*)d_in[3];
    const float* gq = (const float*)d_in[4];
    const float* bq = (const float*)d_in[5];
    const float* mq = (const float*)d_in[6];
    const float* vq = (const float*)d_in[7];
    const float* wk = (const float*)d_in[8];
    const float* gk = (const float*)d_in[9];
    const float* bk = (const float*)d_in[10];
    const float* mk = (const float*)d_in[11];
    const float* vk = (const float*)d_in[12];
    const float* wv = (const float*)d_in[13];
    const float* gv = (const float*)d_in[14];
    const float* bv = (const float*)d_in[15];
    const float* mv = (const float*)d_in[16];
    const float* vv = (const float*)d_in[17];
    const float* pw = (const float*)d_in[18];
    const float* pb = (const float*)d_in[19];
    float* out = (float*)d_out;

    const size_t QKV_ELEMS = (size_t)NB * NH * TP * DH;
    bf16_t* ws = (bf16_t*)d_ws;
    bf16_t* Q  = ws;
    bf16_t* K  = ws + QKV_ELEMS;
    bf16_t* V  = ws + 2 * QKV_ELEMS;
    bf16_t* Vt = ws + 3 * QKV_ELEMS;
    bf16_t* Oa = ws + 4 * QKV_ELEMS;
    bf16_t* Wb = Oa + (size_t)NB * NT * NC;

    conv_w<<<(NC * NC + 255) / 256, 256, 0, stream>>>(pw, Wb);
    qkv_conv<<<dim3(8, 3, NB), 256, 0, stream>>>(
        x, wq, gq, bq, mq, vq, wk, gk, bk, mk, vk, wv, gv, bv, mv, vv, Q, K, V);
    cls_fill<<<(NB * NC) / 256, 256, 0, stream>>>(x, Q, K, V);
    transpose_v<<<dim3(17, NB * NH), 256, 0, stream>>>(V, Vt);
    attn_kernel<<<192 * 33, 128, 0, stream>>>(Q, K, Vt, Oa);
    proj_gemm<<<513 * 12, 64, 0, stream>>>(Oa, Wb, pb, out);
}

// Round 8
// 681.206 us; speedup vs baseline: 1.0076x; 1.0076x over previous
//
#include <hip/hip_runtime.h>

typedef __bf16 bf16_t;
typedef __attribute__((ext_vector_type(8))) __bf16 bf16x8;
typedef __attribute__((ext_vector_type(4))) __bf16 bf16x4;
typedef __attribute__((ext_vector_type(4))) float f32x4;

#define NB 16
#define NC 768
#define NT 1025
#define TP 1088            /* 17 * 64 */
#define NH 12
#define DH 64
#define QK_SCALE 0.03608439182435161f  /* 1/sqrt(768) */

// ---------------- QKV depthwise conv + BN (register-blocked) ----------------
__global__ __launch_bounds__(256) void qkv_conv(
    const float* __restrict__ x,
    const float* __restrict__ wq, const float* __restrict__ gq, const float* __restrict__ bq,
    const float* __restrict__ mq, const float* __restrict__ vq,
    const float* __restrict__ wk, const float* __restrict__ gk, const float* __restrict__ bk,
    const float* __restrict__ mk, const float* __restrict__ vk,
    const float* __restrict__ wv, const float* __restrict__ gv, const float* __restrict__ bv,
    const float* __restrict__ mv, const float* __restrict__ vv,
    bf16_t* __restrict__ Q, bf16_t* __restrict__ K, bf16_t* __restrict__ V)
{
    const int tid = threadIdx.x;
    const int c  = blockIdx.y * 256 + tid;
    const int y0 = blockIdx.x * 4;
    const int b  = blockIdx.z;

    const float* xb = x + ((size_t)b * NT + 1) * NC + c;

    float WQ[9], WK[9], WV[9];
#pragma unroll
    for (int k = 0; k < 9; ++k) {
        WQ[k] = wq[c * 9 + k];
        WK[k] = wk[c * 9 + k];
        WV[k] = wv[c * 9 + k];
    }
    float sq = gq[c] * rsqrtf(vq[c] + 1e-5f);
    float tq = (bq[c] - mq[c] * sq) * QK_SCALE; sq *= QK_SCALE;
    float sk = gk[c] * rsqrtf(vk[c] + 1e-5f);
    float tk = bk[c] - mk[c] * sk;
    float sv = gv[c] * rsqrtf(vv[c] + 1e-5f);
    float tv = bv[c] - mv[c] * sv;

    const int h = c >> 6, dk = c & 63;
    bf16_t* Qo = Q + ((size_t)(b * NH + h) * TP + 1 + y0 * 32) * DH + dk;
    bf16_t* Ko = K + ((size_t)(b * NH + h) * TP + 1 + y0 * 32) * DH + dk;
    bf16_t* Vo = V + ((size_t)(b * NH + h) * TP + 1 + y0 * 32) * DH + dk;

    float win[6][3];
#pragma unroll
    for (int r = 0; r < 6; ++r) {
        int yy = y0 - 1 + r;
        win[r][0] = 0.f;
        win[r][1] = (yy >= 0 && yy < 32) ? xb[(size_t)(yy * 32) * NC] : 0.f;
    }

#pragma unroll 4
    for (int xo = 0; xo < 32; ++xo) {
#pragma unroll
        for (int r = 0; r < 6; ++r) {
            int yy = y0 - 1 + r;
            win[r][2] = (xo < 31 && yy >= 0 && yy < 32)
                        ? xb[(size_t)(yy * 32 + xo + 1) * NC] : 0.f;
        }
#pragma unroll
        for (int r = 0; r < 4; ++r) {
            float aq = 0.f, ak = 0.f, av = 0.f;
#pragma unroll
            for (int dy = 0; dy < 3; ++dy) {
#pragma unroll
                for (int dx = 0; dx < 3; ++dx) {
                    float xv = win[r + dy][dx];
                    aq += xv * WQ[dy * 3 + dx];
                    ak += xv * WK[dy * 3 + dx];
                    av += xv * WV[dy * 3 + dx];
                }
            }
            size_t o = ((size_t)(r * 32 + xo)) * DH;
            Qo[o] = (bf16_t)(aq * sq + tq);
            Ko[o] = (bf16_t)(ak * sk + tk);
            Vo[o] = (bf16_t)(av * sv + tv);
        }
#pragma unroll
        for (int r = 0; r < 6; ++r) {
            win[r][0] = win[r][1];
            win[r][1] = win[r][2];
        }
    }
}

__global__ __launch_bounds__(256) void cls_fill(
    const float* __restrict__ x, bf16_t* __restrict__ Q, bf16_t* __restrict__ K, bf16_t* __restrict__ V)
{
    int idx = blockIdx.x * 256 + threadIdx.x;
    int c = idx % NC;
    int b = idx / NC;
    float xv = x[(size_t)b * NT * NC + c];
    int h = c >> 6, dk = c & 63;
    size_t base = ((size_t)(b * NH + h) * TP + 0) * DH + dk;
    Q[base] = (bf16_t)(xv * QK_SCALE);
    K[base] = (bf16_t)xv;
    V[base] = (bf16_t)xv;
}

// ---------------- V transpose: [bh][t][64] -> [bh][64][t] ----------------
__global__ __launch_bounds__(256) void transpose_v(
    const bf16_t* __restrict__ V, bf16_t* __restrict__ Vt)
{
    __shared__ bf16_t tile[64][65];
    int bh = blockIdx.y;
    int t0 = blockIdx.x * 64;
    for (int i = threadIdx.x; i < 64 * 64; i += 256) {
        int tt = i >> 6, dk = i & 63;
        tile[tt][dk] = V[((size_t)bh * TP + t0 + tt) * DH + dk];
    }
    __syncthreads();
    for (int i = threadIdx.x; i < 64 * 64; i += 256) {
        int dk = i >> 6, tt = i & 63;
        Vt[((size_t)bh * DH + dk) * TP + t0 + tt] = tile[tt][dk];
    }
}

// ---------------- flash attention (swapped QK^T, all-register P) ----------------
// S^T = mfma(K_frag, Q_frag): lane (cl,gr) owns q-row cl. Physical key row
// fed to A-fragment row m of tile (b32,tau) is phi(m) = (m>>2)*8 + tau*4 + (m&3),
// so the lane's 16 exp'd scores are EXACTLY PV's B-fragment (keys gr*8..gr*8+7
// per 32-block). Softmax = in-lane trees + 2 shfl_xor. No LDS, no barriers.
__global__ __launch_bounds__(128) void attn_kernel(
    const bf16_t* __restrict__ Q, const bf16_t* __restrict__ K,
    const bf16_t* __restrict__ Vt, bf16_t* __restrict__ Oa)
{
    int bid = blockIdx.x;                       // 6336
    int swz = (bid & 7) * 792 + (bid >> 3);     // 8 XCDs
    int bh = swz / 33;
    int qp = swz % 33;
    int wid = threadIdx.x >> 6;
    int lane = threadIdx.x & 63;
    int qt = qp * 2 + wid;                      // 0..65
    int b = bh / NH, h = bh % NH;
    int cl = lane & 15, gr = lane >> 4;

    const bf16_t* Qb = Q + ((size_t)bh * TP + qt * 16) * DH;
    const bf16_t* Kb = K + (size_t)bh * TP * DH;
    const bf16_t* Vb = Vt + (size_t)bh * DH * TP;

    // Q as B-fragment: B[k=dh][n=qrow]; n = cl -> load Q row cl
    bf16x8 qf0 = *(const bf16x8*)(Qb + cl * DH + gr * 8);
    bf16x8 qf1 = *(const bf16x8*)(Qb + cl * DH + 32 + gr * 8);

    f32x4 o0 = {0.f, 0.f, 0.f, 0.f}, o1 = o0, o2 = o0, o3 = o0;
    float mrow = -1e30f, lrow = 0.f;

    const int phi = ((cl >> 2) << 3) + (cl & 3);   // A-row -> physical key offset

    for (int kt = 0; kt < 17; ++kt) {
        int t0 = kt * 64;
        f32x4 s[2][2];
#pragma unroll
        for (int b32 = 0; b32 < 2; ++b32)
#pragma unroll
        for (int tau = 0; tau < 2; ++tau) {
            const bf16_t* K0 = Kb + (size_t)(t0 + b32 * 32 + tau * 4 + phi) * DH + gr * 8;
            f32x4 acc = {0.f, 0.f, 0.f, 0.f};
            acc = __builtin_amdgcn_mfma_f32_16x16x32_bf16(*(const bf16x8*)K0,        qf0, acc, 0, 0, 0);
            acc = __builtin_amdgcn_mfma_f32_16x16x32_bf16(*(const bf16x8*)(K0 + 32), qf1, acc, 0, 0, 0);
            s[b32][tau] = acc;
        }
        // mask padded keys: D-row m=gr*4+j holds key t0 + b32*32 + gr*8 + tau*4 + j
#pragma unroll
        for (int b32 = 0; b32 < 2; ++b32)
#pragma unroll
        for (int tau = 0; tau < 2; ++tau)
#pragma unroll
        for (int j = 0; j < 4; ++j)
            if (t0 + b32 * 32 + gr * 8 + tau * 4 + j >= NT) s[b32][tau][j] = -1e30f;

        // in-lane row max (16 values), then across gr groups
        float m0 = fmaxf(fmaxf(s[0][0][0], s[0][0][1]), fmaxf(s[0][0][2], s[0][0][3]));
        float m1 = fmaxf(fmaxf(s[0][1][0], s[0][1][1]), fmaxf(s[0][1][2], s[0][1][3]));
        float m2 = fmaxf(fmaxf(s[1][0][0], s[1][0][1]), fmaxf(s[1][0][2], s[1][0][3]));
        float m3 = fmaxf(fmaxf(s[1][1][0], s[1][1][1]), fmaxf(s[1][1][2], s[1][1][3]));
        float mx = fmaxf(fmaxf(m0, m1), fmaxf(m2, m3));
        mx = fmaxf(mx, __shfl_xor(mx, 16));
        mx = fmaxf(mx, __shfl_xor(mx, 32));

        bool need = mx > mrow + 8.f;            // defer-max (T13)
        if (__ballot(need)) {
            float mn = fmaxf(mrow, mx);
            float al = __expf(mrow - mn);
            mrow = mn;
            lrow *= al;
#pragma unroll
            for (int j = 0; j < 4; ++j) { o0[j] *= al; o1[j] *= al; o2[j] *= al; o3[j] *= al; }
        }

        // exp (in place) + in-lane sum tree + cross-gr reduce
#pragma unroll
        for (int b32 = 0; b32 < 2; ++b32)
#pragma unroll
        for (int tau = 0; tau < 2; ++tau)
#pragma unroll
        for (int j = 0; j < 4; ++j)
            s[b32][tau][j] = __expf(s[b32][tau][j] - mrow);
        float r0 = (s[0][0][0] + s[0][0][1]) + (s[0][0][2] + s[0][0][3]);
        float r1 = (s[0][1][0] + s[0][1][1]) + (s[0][1][2] + s[0][1][3]);
        float r2 = (s[1][0][0] + s[1][0][1]) + (s[1][0][2] + s[1][0][3]);
        float r3 = (s[1][1][0] + s[1][1][1]) + (s[1][1][2] + s[1][1][3]);
        float rs = (r0 + r1) + (r2 + r3);
        rs += __shfl_xor(rs, 16);
        rs += __shfl_xor(rs, 32);
        lrow += rs;

        // pack P into PV B-fragments: element e of block b32 -> key gr*8+e
#pragma unroll
        for (int b32 = 0; b32 < 2; ++b32) {
            bf16x8 pf;
#pragma unroll
            for (int j = 0; j < 4; ++j) {
                pf[j]     = (bf16_t)s[b32][0][j];
                pf[4 + j] = (bf16_t)s[b32][1][j];
            }
            const bf16_t* V0 = Vb + t0 + b32 * 32 + gr * 8;
            o0 = __builtin_amdgcn_mfma_f32_16x16x32_bf16(*(const bf16x8*)(V0 + (size_t)(0 * 16 + cl) * TP), pf, o0, 0, 0, 0);
            o1 = __builtin_amdgcn_mfma_f32_16x16x32_bf16(*(const bf16x8*)(V0 + (size_t)(1 * 16 + cl) * TP), pf, o1, 0, 0, 0);
            o2 = __builtin_amdgcn_mfma_f32_16x16x32_bf16(*(const bf16x8*)(V0 + (size_t)(2 * 16 + cl) * TP), pf, o2, 0, 0, 0);
            o3 = __builtin_amdgcn_mfma_f32_16x16x32_bf16(*(const bf16x8*)(V0 + (size_t)(3 * 16 + cl) * TP), pf, o3, 0, 0, 0);
        }
    }

    // lane (cl,gr) holds O[q=qt*16+cl][d = dblk*16 + gr*4 + j]
    int qrow = qt * 16 + cl;
    if (qrow < NT) {
        float inv = 1.0f / lrow;
        bf16_t* orow = Oa + ((size_t)b * NT + qrow) * NC + h * DH + gr * 4;
        bf16x4 w0, w1, w2, w3;
#pragma unroll
        for (int j = 0; j < 4; ++j) {
            w0[j] = (bf16_t)(o0[j] * inv);
            w1[j] = (bf16_t)(o1[j] * inv);
            w2[j] = (bf16_t)(o2[j] * inv);
            w3[j] = (bf16_t)(o3[j] * inv);
        }
        *(bf16x4*)(orow + 0)  = w0;
        *(bf16x4*)(orow + 16) = w1;
        *(bf16x4*)(orow + 32) = w2;
        *(bf16x4*)(orow + 48) = w3;
    }
}

__global__ __launch_bounds__(256) void conv_w(const float* __restrict__ W, bf16_t* __restrict__ Wb)
{
    int i = blockIdx.x * 256 + threadIdx.x;
    if (i < NC * NC) Wb[i] = (bf16_t)W[i];
}

// ---------------- projection GEMM: 32-row waves, B-frags shared ----------------
__global__ __launch_bounds__(64) void proj_gemm(
    const bf16_t* __restrict__ Oa, const bf16_t* __restrict__ Wb,
    const float* __restrict__ bias, float* __restrict__ out)
{
    int wid = blockIdx.x;          // 513 * 12
    int nt = wid % 12;
    int mt = wid / 12;
    int lane = threadIdx.x;
    int cl = lane & 15, gr = lane >> 4;

    const bf16_t* A0 = Oa + ((size_t)mt * 32 + cl) * NC + gr * 8;
    const bf16_t* A1 = A0 + (size_t)16 * NC;
    const bf16_t* Bp = Wb + ((size_t)(nt * 64 + cl)) * NC + gr * 8;
    f32x4 acc[2][4];
#pragma unroll
    for (int a = 0; a < 2; ++a)
#pragma unroll
        for (int j = 0; j < 4; ++j) { acc[a][j][0]=0.f; acc[a][j][1]=0.f; acc[a][j][2]=0.f; acc[a][j][3]=0.f; }
#pragma unroll 2
    for (int ks = 0; ks < 24; ++ks) {
        bf16x8 af0 = *(const bf16x8*)(A0 + ks * 32);
        bf16x8 af1 = *(const bf16x8*)(A1 + ks * 32);
#pragma unroll
        for (int j = 0; j < 4; ++j) {
            bf16x8 bf = *(const bf16x8*)(Bp + (size_t)j * 16 * NC + ks * 32);
            acc[0][j] = __builtin_amdgcn_mfma_f32_16x16x32_bf16(af0, bf, acc[0][j], 0, 0, 0);
            acc[1][j] = __builtin_amdgcn_mfma_f32_16x16x32_bf16(af1, bf, acc[1][j], 0, 0, 0);
        }
    }
#pragma unroll
    for (int a = 0; a < 2; ++a)
#pragma unroll
    for (int j = 0; j < 4; ++j) {
        int col = nt * 64 + j * 16 + cl;
        float bv = bias[col];
#pragma unroll
        for (int jj = 0; jj < 4; ++jj) {
            int r = mt * 32 + a * 16 + gr * 4 + jj;
            if (r < NB * NT)
                out[(size_t)r * NC + col] = acc[a][j][jj] + bv;
        }
    }
}

extern "C" void kernel_launch(void* const* d_in, const int* in_sizes, int n_in,
                              void* d_out, int out_size, void* d_ws, size_t ws_size,
                              hipStream_t stream)
{
    const float* x = (const float*)d_in[0];
    const float* wq = (const float*)d_in[3];
    const float* gq = (const float*)d_in[4];
    const float* bq = (const float*)d_in[5];
    const float* mq = (const float*)d_in[6];
    const float* vq = (const float*)d_in[7];
    const float* wk = (const float*)d_in[8];
    const float* gk = (const float*)d_in[9];
    const float* bk = (const float*)d_in[10];
    const float* mk = (const float*)d_in[11];
    const float* vk = (const float*)d_in[12];
    const float* wv = (const float*)d_in[13];
    const float* gv = (const float*)d_in[14];
    const float* bv = (const float*)d_in[15];
    const float* mv = (const float*)d_in[16];
    const float* vv = (const float*)d_in[17];
    const float* pw = (const float*)d_in[18];
    const float* pb = (const float*)d_in[19];
    float* out = (float*)d_out;

    const size_t QKV_ELEMS = (size_t)NB * NH * TP * DH;
    bf16_t* ws = (bf16_t*)d_ws;
    bf16_t* Q  = ws;
    bf16_t* K  = ws + QKV_ELEMS;
    bf16_t* V  = ws + 2 * QKV_ELEMS;
    bf16_t* Vt = ws + 3 * QKV_ELEMS;
    bf16_t* Oa = ws + 4 * QKV_ELEMS;
    bf16_t* Wb = Oa + (size_t)NB * NT * NC;

    conv_w<<<(NC * NC + 255) / 256, 256, 0, stream>>>(pw, Wb);
    qkv_conv<<<dim3(8, 3, NB), 256, 0, stream>>>(
        x, wq, gq, bq, mq, vq, wk, gk, bk, mk, vk, wv, gv, bv, mv, vv, Q, K, V);
    cls_fill<<<(NB * NC) / 256, 256, 0, stream>>>(x, Q, K, V);
    transpose_v<<<dim3(17, NB * NH), 256, 0, stream>>>(V, Vt);
    attn_kernel<<<192 * 33, 128, 0, stream>>>(Q, K, Vt, Oa);
    proj_gemm<<<513 * 12, 64, 0, stream>>>(Oa, Wb, pb, out);
}

// Round 9
// 494.971 us; speedup vs baseline: 1.3867x; 1.3763x over previous
//
#include <hip/hip_runtime.h>

typedef __bf16 bf16_t;
typedef __attribute__((ext_vector_type(8))) __bf16 bf16x8;
typedef __attribute__((ext_vector_type(4))) __bf16 bf16x4;
typedef __attribute__((ext_vector_type(4))) float f32x4;

#define NB 16
#define NC 768
#define NT 1025
#define TP 1088            /* 17 * 64 */
#define NH 12
#define DH 64
#define QK_SCALE 0.03608439182435161f  /* 1/sqrt(768) */

// ---------------- QKV depthwise conv + BN (register-blocked) ----------------
__global__ __launch_bounds__(256) void qkv_conv(
    const float* __restrict__ x,
    const float* __restrict__ wq, const float* __restrict__ gq, const float* __restrict__ bq,
    const float* __restrict__ mq, const float* __restrict__ vq,
    const float* __restrict__ wk, const float* __restrict__ gk, const float* __restrict__ bk,
    const float* __restrict__ mk, const float* __restrict__ vk,
    const float* __restrict__ wv, const float* __restrict__ gv, const float* __restrict__ bv,
    const float* __restrict__ mv, const float* __restrict__ vv,
    bf16_t* __restrict__ Q, bf16_t* __restrict__ K, bf16_t* __restrict__ V)
{
    const int tid = threadIdx.x;
    const int c  = blockIdx.y * 256 + tid;
    const int y0 = blockIdx.x * 4;
    const int b  = blockIdx.z;

    const float* xb = x + ((size_t)b * NT + 1) * NC + c;

    float WQ[9], WK[9], WV[9];
#pragma unroll
    for (int k = 0; k < 9; ++k) {
        WQ[k] = wq[c * 9 + k];
        WK[k] = wk[c * 9 + k];
        WV[k] = wv[c * 9 + k];
    }
    float sq = gq[c] * rsqrtf(vq[c] + 1e-5f);
    float tq = (bq[c] - mq[c] * sq) * QK_SCALE; sq *= QK_SCALE;
    float sk = gk[c] * rsqrtf(vk[c] + 1e-5f);
    float tk = bk[c] - mk[c] * sk;
    float sv = gv[c] * rsqrtf(vv[c] + 1e-5f);
    float tv = bv[c] - mv[c] * sv;

    const int h = c >> 6, dk = c & 63;
    bf16_t* Qo = Q + ((size_t)(b * NH + h) * TP + 1 + y0 * 32) * DH + dk;
    bf16_t* Ko = K + ((size_t)(b * NH + h) * TP + 1 + y0 * 32) * DH + dk;
    bf16_t* Vo = V + ((size_t)(b * NH + h) * TP + 1 + y0 * 32) * DH + dk;

    float win[6][3];
#pragma unroll
    for (int r = 0; r < 6; ++r) {
        int yy = y0 - 1 + r;
        win[r][0] = 0.f;
        win[r][1] = (yy >= 0 && yy < 32) ? xb[(size_t)(yy * 32) * NC] : 0.f;
    }

#pragma unroll 4
    for (int xo = 0; xo < 32; ++xo) {
#pragma unroll
        for (int r = 0; r < 6; ++r) {
            int yy = y0 - 1 + r;
            win[r][2] = (xo < 31 && yy >= 0 && yy < 32)
                        ? xb[(size_t)(yy * 32 + xo + 1) * NC] : 0.f;
        }
#pragma unroll
        for (int r = 0; r < 4; ++r) {
            float aq = 0.f, ak = 0.f, av = 0.f;
#pragma unroll
            for (int dy = 0; dy < 3; ++dy) {
#pragma unroll
                for (int dx = 0; dx < 3; ++dx) {
                    float xv = win[r + dy][dx];
                    aq += xv * WQ[dy * 3 + dx];
                    ak += xv * WK[dy * 3 + dx];
                    av += xv * WV[dy * 3 + dx];
                }
            }
            size_t o = ((size_t)(r * 32 + xo)) * DH;
            Qo[o] = (bf16_t)(aq * sq + tq);
            Ko[o] = (bf16_t)(ak * sk + tk);
            Vo[o] = (bf16_t)(av * sv + tv);
        }
#pragma unroll
        for (int r = 0; r < 6; ++r) {
            win[r][0] = win[r][1];
            win[r][1] = win[r][2];
        }
    }
}

__global__ __launch_bounds__(256) void cls_fill(
    const float* __restrict__ x, bf16_t* __restrict__ Q, bf16_t* __restrict__ K, bf16_t* __restrict__ V)
{
    int idx = blockIdx.x * 256 + threadIdx.x;
    int c = idx % NC;
    int b = idx / NC;
    float xv = x[(size_t)b * NT * NC + c];
    int h = c >> 6, dk = c & 63;
    size_t base = ((size_t)(b * NH + h) * TP + 0) * DH + dk;
    Q[base] = (bf16_t)(xv * QK_SCALE);
    K[base] = (bf16_t)xv;
    V[base] = (bf16_t)xv;
}

// ---------------- V transpose: [bh][t][64] -> [bh][64][t] ----------------
__global__ __launch_bounds__(256) void transpose_v(
    const bf16_t* __restrict__ V, bf16_t* __restrict__ Vt)
{
    __shared__ bf16_t tile[64][65];
    int bh = blockIdx.y;
    int t0 = blockIdx.x * 64;
    for (int i = threadIdx.x; i < 64 * 64; i += 256) {
        int tt = i >> 6, dk = i & 63;
        tile[tt][dk] = V[((size_t)bh * TP + t0 + tt) * DH + dk];
    }
    __syncthreads();
    for (int i = threadIdx.x; i < 64 * 64; i += 256) {
        int dk = i >> 6, tt = i & 63;
        Vt[((size_t)bh * DH + dk) * TP + t0 + tt] = tile[tt][dk];
    }
}

// ---------------- flash attention (swapped QK^T, register P, K-prefetch) ----------------
// Each wave owns 32 q-rows (2 16-row tiles A/B) of one (b,h): K/V loads amortized
// over 2x MFMA. K double-buffered in registers (issue K(t+1) right after QK(t));
// V issued at iteration top, consumed at its end. launch_bounds(128,2) gives the
// VGPR headroom (r8's 56-VGPR/no-prefetch build was latency-bound at 414us).
__global__ __launch_bounds__(128, 2) void attn_kernel(
    const bf16_t* __restrict__ Q, const bf16_t* __restrict__ K,
    const bf16_t* __restrict__ Vt, bf16_t* __restrict__ Oa)
{
    int bid = blockIdx.x;                       // 3168 = 8 * 396
    int swz = (bid & 7) * 396 + (bid >> 3);     // bijective XCD swizzle
    int u = swz * 2 + (threadIdx.x >> 6);       // wave unit 0..6335
    int bh = u / 33;
    int qw = u % 33;                            // 32-row q tile
    int b = bh / NH, h = bh % NH;
    int lane = threadIdx.x & 63;
    int cl = lane & 15, gr = lane >> 4;

    const bf16_t* Qb = Q + ((size_t)bh * TP + qw * 32) * DH;
    const bf16_t* Kb = K + (size_t)bh * TP * DH;
    const bf16_t* Vb = Vt + (size_t)bh * DH * TP;

    bf16x8 qa0 = *(const bf16x8*)(Qb + cl * DH + gr * 8);
    bf16x8 qa1 = *(const bf16x8*)(Qb + cl * DH + 32 + gr * 8);
    bf16x8 qb0 = *(const bf16x8*)(Qb + (16 + cl) * DH + gr * 8);
    bf16x8 qb1 = *(const bf16x8*)(Qb + (16 + cl) * DH + 32 + gr * 8);

    f32x4 oa0 = {0.f,0.f,0.f,0.f}, oa1 = oa0, oa2 = oa0, oa3 = oa0;
    f32x4 ob0 = oa0, ob1 = oa0, ob2 = oa0, ob3 = oa0;
    float mA = -1e30f, lA = 0.f, mB = -1e30f, lB = 0.f;

    const int phi = ((cl >> 2) << 3) + (cl & 3);   // A-row -> physical key offset

    bf16x8 kA[4][2], kB[4][2];                     // ping-pong K tiles (bt = b32*2+tau)

#pragma unroll
    for (int bt = 0; bt < 4; ++bt) {               // prologue: K(0)
        const bf16_t* K0 = Kb + (size_t)((bt >> 1) * 32 + (bt & 1) * 4 + phi) * DH + gr * 8;
        kA[bt][0] = *(const bf16x8*)K0;
        kA[bt][1] = *(const bf16x8*)(K0 + 32);
    }

    auto body = [&](bf16x8 (&kc)[4][2], bf16x8 (&kn)[4][2], int kt) {
        int t0 = kt * 64;
        // V(t): issue now, consume at iteration end
        bf16x8 vv[2][4];
#pragma unroll
        for (int b32 = 0; b32 < 2; ++b32)
#pragma unroll
        for (int d = 0; d < 4; ++d)
            vv[b32][d] = *(const bf16x8*)(Vb + (size_t)(d * 16 + cl) * TP + t0 + b32 * 32 + gr * 8);

        // QK^T for both q-tiles
        f32x4 sa[4], sb[4];
#pragma unroll
        for (int bt = 0; bt < 4; ++bt) {
            f32x4 z = {0.f,0.f,0.f,0.f};
            sa[bt] = __builtin_amdgcn_mfma_f32_16x16x32_bf16(kc[bt][0], qa0, z, 0, 0, 0);
            sa[bt] = __builtin_amdgcn_mfma_f32_16x16x32_bf16(kc[bt][1], qa1, sa[bt], 0, 0, 0);
            sb[bt] = __builtin_amdgcn_mfma_f32_16x16x32_bf16(kc[bt][0], qb0, z, 0, 0, 0);
            sb[bt] = __builtin_amdgcn_mfma_f32_16x16x32_bf16(kc[bt][1], qb1, sb[bt], 0, 0, 0);
        }

        // prefetch K(t+1) into the other buffer
        if (kt < 16) {
#pragma unroll
            for (int bt = 0; bt < 4; ++bt) {
                const bf16_t* K0 = Kb + (size_t)(t0 + 64 + (bt >> 1) * 32 + (bt & 1) * 4 + phi) * DH + gr * 8;
                kn[bt][0] = *(const bf16x8*)K0;
                kn[bt][1] = *(const bf16x8*)(K0 + 32);
            }
        }

        // mask padded keys (only final tile has any)
        if (t0 + 64 > NT) {
#pragma unroll
            for (int bt = 0; bt < 4; ++bt)
#pragma unroll
            for (int j = 0; j < 4; ++j) {
                int key = t0 + (bt >> 1) * 32 + gr * 8 + (bt & 1) * 4 + j;
                if (key >= NT) { sa[bt][j] = -1e30f; sb[bt][j] = -1e30f; }
            }
        }

        // softmax tile A
        {
            float m0 = fmaxf(fmaxf(sa[0][0], sa[0][1]), fmaxf(sa[0][2], sa[0][3]));
            float m1 = fmaxf(fmaxf(sa[1][0], sa[1][1]), fmaxf(sa[1][2], sa[1][3]));
            float m2 = fmaxf(fmaxf(sa[2][0], sa[2][1]), fmaxf(sa[2][2], sa[2][3]));
            float m3 = fmaxf(fmaxf(sa[3][0], sa[3][1]), fmaxf(sa[3][2], sa[3][3]));
            float mx = fmaxf(fmaxf(m0, m1), fmaxf(m2, m3));
            mx = fmaxf(mx, __shfl_xor(mx, 16));
            mx = fmaxf(mx, __shfl_xor(mx, 32));
            if (__ballot(mx > mA + 8.f)) {
                float mn = fmaxf(mA, mx);
                float al = __expf(mA - mn);
                mA = mn; lA *= al;
#pragma unroll
                for (int j = 0; j < 4; ++j) { oa0[j] *= al; oa1[j] *= al; oa2[j] *= al; oa3[j] *= al; }
            }
#pragma unroll
            for (int bt = 0; bt < 4; ++bt)
#pragma unroll
            for (int j = 0; j < 4; ++j)
                sa[bt][j] = __expf(sa[bt][j] - mA);
            float r0 = (sa[0][0] + sa[0][1]) + (sa[0][2] + sa[0][3]);
            float r1 = (sa[1][0] + sa[1][1]) + (sa[1][2] + sa[1][3]);
            float r2 = (sa[2][0] + sa[2][1]) + (sa[2][2] + sa[2][3]);
            float r3 = (sa[3][0] + sa[3][1]) + (sa[3][2] + sa[3][3]);
            float rs = (r0 + r1) + (r2 + r3);
            rs += __shfl_xor(rs, 16);
            rs += __shfl_xor(rs, 32);
            lA += rs;
        }
        // softmax tile B
        {
            float m0 = fmaxf(fmaxf(sb[0][0], sb[0][1]), fmaxf(sb[0][2], sb[0][3]));
            float m1 = fmaxf(fmaxf(sb[1][0], sb[1][1]), fmaxf(sb[1][2], sb[1][3]));
            float m2 = fmaxf(fmaxf(sb[2][0], sb[2][1]), fmaxf(sb[2][2], sb[2][3]));
            float m3 = fmaxf(fmaxf(sb[3][0], sb[3][1]), fmaxf(sb[3][2], sb[3][3]));
            float mx = fmaxf(fmaxf(m0, m1), fmaxf(m2, m3));
            mx = fmaxf(mx, __shfl_xor(mx, 16));
            mx = fmaxf(mx, __shfl_xor(mx, 32));
            if (__ballot(mx > mB + 8.f)) {
                float mn = fmaxf(mB, mx);
                float al = __expf(mB - mn);
                mB = mn; lB *= al;
#pragma unroll
                for (int j = 0; j < 4; ++j) { ob0[j] *= al; ob1[j] *= al; ob2[j] *= al; ob3[j] *= al; }
            }
#pragma unroll
            for (int bt = 0; bt < 4; ++bt)
#pragma unroll
            for (int j = 0; j < 4; ++j)
                sb[bt][j] = __expf(sb[bt][j] - mB);
            float r0 = (sb[0][0] + sb[0][1]) + (sb[0][2] + sb[0][3]);
            float r1 = (sb[1][0] + sb[1][1]) + (sb[1][2] + sb[1][3]);
            float r2 = (sb[2][0] + sb[2][1]) + (sb[2][2] + sb[2][3]);
            float r3 = (sb[3][0] + sb[3][1]) + (sb[3][2] + sb[3][3]);
            float rs = (r0 + r1) + (r2 + r3);
            rs += __shfl_xor(rs, 16);
            rs += __shfl_xor(rs, 32);
            lB += rs;
        }

        // pack P -> PV B-fragments and accumulate (consumes vv)
#pragma unroll
        for (int b32 = 0; b32 < 2; ++b32) {
            bf16x8 pa, pb;
#pragma unroll
            for (int j = 0; j < 4; ++j) {
                pa[j]     = (bf16_t)sa[b32 * 2 + 0][j];
                pa[4 + j] = (bf16_t)sa[b32 * 2 + 1][j];
                pb[j]     = (bf16_t)sb[b32 * 2 + 0][j];
                pb[4 + j] = (bf16_t)sb[b32 * 2 + 1][j];
            }
            oa0 = __builtin_amdgcn_mfma_f32_16x16x32_bf16(vv[b32][0], pa, oa0, 0, 0, 0);
            oa1 = __builtin_amdgcn_mfma_f32_16x16x32_bf16(vv[b32][1], pa, oa1, 0, 0, 0);
            oa2 = __builtin_amdgcn_mfma_f32_16x16x32_bf16(vv[b32][2], pa, oa2, 0, 0, 0);
            oa3 = __builtin_amdgcn_mfma_f32_16x16x32_bf16(vv[b32][3], pa, oa3, 0, 0, 0);
            ob0 = __builtin_amdgcn_mfma_f32_16x16x32_bf16(vv[b32][0], pb, ob0, 0, 0, 0);
            ob1 = __builtin_amdgcn_mfma_f32_16x16x32_bf16(vv[b32][1], pb, ob1, 0, 0, 0);
            ob2 = __builtin_amdgcn_mfma_f32_16x16x32_bf16(vv[b32][2], pb, ob2, 0, 0, 0);
            ob3 = __builtin_amdgcn_mfma_f32_16x16x32_bf16(vv[b32][3], pb, ob3, 0, 0, 0);
        }
    };

#pragma unroll 1
    for (int i = 0; i < 8; ++i) {
        body(kA, kB, 2 * i);
        body(kB, kA, 2 * i + 1);
    }
    body(kA, kB, 16);

    // epilogue: lane (cl,gr) holds O[q][d = dblk*16 + gr*4 + j]
    {
        int qrow = qw * 32 + cl;
        if (qrow < NT) {
            float inv = 1.0f / lA;
            bf16_t* orow = Oa + ((size_t)b * NT + qrow) * NC + h * DH + gr * 4;
            bf16x4 w0, w1, w2, w3;
#pragma unroll
            for (int j = 0; j < 4; ++j) {
                w0[j] = (bf16_t)(oa0[j] * inv);
                w1[j] = (bf16_t)(oa1[j] * inv);
                w2[j] = (bf16_t)(oa2[j] * inv);
                w3[j] = (bf16_t)(oa3[j] * inv);
            }
            *(bf16x4*)(orow + 0)  = w0;
            *(bf16x4*)(orow + 16) = w1;
            *(bf16x4*)(orow + 32) = w2;
            *(bf16x4*)(orow + 48) = w3;
        }
    }
    {
        int qrow = qw * 32 + 16 + cl;
        if (qrow < NT) {
            float inv = 1.0f / lB;
            bf16_t* orow = Oa + ((size_t)b * NT + qrow) * NC + h * DH + gr * 4;
            bf16x4 w0, w1, w2, w3;
#pragma unroll
            for (int j = 0; j < 4; ++j) {
                w0[j] = (bf16_t)(ob0[j] * inv);
                w1[j] = (bf16_t)(ob1[j] * inv);
                w2[j] = (bf16_t)(ob2[j] * inv);
                w3[j] = (bf16_t)(ob3[j] * inv);
            }
            *(bf16x4*)(orow + 0)  = w0;
            *(bf16x4*)(orow + 16) = w1;
            *(bf16x4*)(orow + 32) = w2;
            *(bf16x4*)(orow + 48) = w3;
        }
    }
}

__global__ __launch_bounds__(256) void conv_w(const float* __restrict__ W, bf16_t* __restrict__ Wb)
{
    int i = blockIdx.x * 256 + threadIdx.x;
    if (i < NC * NC) Wb[i] = (bf16_t)W[i];
}

// ---------------- projection GEMM: 32-row waves, B-frags shared ----------------
__global__ __launch_bounds__(64) void proj_gemm(
    const bf16_t* __restrict__ Oa, const bf16_t* __restrict__ Wb,
    const float* __restrict__ bias, float* __restrict__ out)
{
    int wid = blockIdx.x;          // 513 * 12
    int nt = wid % 12;
    int mt = wid / 12;
    int lane = threadIdx.x;
    int cl = lane & 15, gr = lane >> 4;

    const bf16_t* A0 = Oa + ((size_t)mt * 32 + cl) * NC + gr * 8;
    const bf16_t* A1 = A0 + (size_t)16 * NC;
    const bf16_t* Bp = Wb + ((size_t)(nt * 64 + cl)) * NC + gr * 8;
    f32x4 acc[2][4];
#pragma unroll
    for (int a = 0; a < 2; ++a)
#pragma unroll
        for (int j = 0; j < 4; ++j) { acc[a][j][0]=0.f; acc[a][j][1]=0.f; acc[a][j][2]=0.f; acc[a][j][3]=0.f; }
#pragma unroll 2
    for (int ks = 0; ks < 24; ++ks) {
        bf16x8 af0 = *(const bf16x8*)(A0 + ks * 32);
        bf16x8 af1 = *(const bf16x8*)(A1 + ks * 32);
#pragma unroll
        for (int j = 0; j < 4; ++j) {
            bf16x8 bf = *(const bf16x8*)(Bp + (size_t)j * 16 * NC + ks * 32);
            acc[0][j] = __builtin_amdgcn_mfma_f32_16x16x32_bf16(af0, bf, acc[0][j], 0, 0, 0);
            acc[1][j] = __builtin_amdgcn_mfma_f32_16x16x32_bf16(af1, bf, acc[1][j], 0, 0, 0);
        }
    }
#pragma unroll
    for (int a = 0; a < 2; ++a)
#pragma unroll
    for (int j = 0; j < 4; ++j) {
        int col = nt * 64 + j * 16 + cl;
        float bv = bias[col];
#pragma unroll
        for (int jj = 0; jj < 4; ++jj) {
            int r = mt * 32 + a * 16 + gr * 4 + jj;
            if (r < NB * NT)
                out[(size_t)r * NC + col] = acc[a][j][jj] + bv;
        }
    }
}

extern "C" void kernel_launch(void* const* d_in, const int* in_sizes, int n_in,
                              void* d_out, int out_size, void* d_ws, size_t ws_size,
                              hipStream_t stream)
{
    const float* x = (const float*)d_in[0];
    const float* wq = (const float*)d_in[3];
    const float* gq = (const float*)d_in[4];
    const float* bq = (const float*)d_in[5];
    const float* mq = (const float*)d_in[6];
    const float* vq = (const float*)d_in[7];
    const float* wk = (const float*)d_in[8];
    const float* gk = (const float*)d_in[9];
    const float* bk = (const float*)d_in[10];
    const float* mk = (const float*)d_in[11];
    const float* vk = (const float*)d_in[12];
    const float* wv = (const float*)d_in[13];
    const float* gv = (const float*)d_in[14];
    const float* bv = (const float*)d_in[15];
    const float* mv = (const float*)d_in[16];
    const float* vv = (const float*)d_in[17];
    const float* pw = (const float*)d_in[18];
    const float* pb = (const float*)d_in[19];
    float* out = (float*)d_out;

    const size_t QKV_ELEMS = (size_t)NB * NH * TP * DH;
    bf16_t* ws = (bf16_t*)d_ws;
    bf16_t* Q  = ws;
    bf16_t* K  = ws + QKV_ELEMS;
    bf16_t* V  = ws + 2 * QKV_ELEMS;
    bf16_t* Vt = ws + 3 * QKV_ELEMS;
    bf16_t* Oa = ws + 4 * QKV_ELEMS;
    bf16_t* Wb = Oa + (size_t)NB * NT * NC;

    conv_w<<<(NC * NC + 255) / 256, 256, 0, stream>>>(pw, Wb);
    qkv_conv<<<dim3(8, 3, NB), 256, 0, stream>>>(
        x, wq, gq, bq, mq, vq, wk, gk, bk, mk, vk, wv, gv, bv, mv, vv, Q, K, V);
    cls_fill<<<(NB * NC) / 256, 256, 0, stream>>>(x, Q, K, V);
    transpose_v<<<dim3(17, NB * NH), 256, 0, stream>>>(V, Vt);
    attn_kernel<<<3168, 128, 0, stream>>>(Q, K, Vt, Oa);
    proj_gemm<<<513 * 12, 64, 0, stream>>>(Oa, Wb, pb, out);
}